// Round 10
// baseline (210.506 us; speedup 1.0000x reference)
//
#include <hip/hip_runtime.h>
#include <math.h>

#define BB 4
#define HH 64
#define WW 64
#define CC 256
#define NN 4096   // H*W
#define MM 1024   // (H/2)*(W/2)
#define LN_EPS 1e-6f
#define SLF (0.17677669529663687f * 1.4426950408889634f)

typedef __attribute__((ext_vector_type(8)))  short short8;
typedef __attribute__((ext_vector_type(16))) float f32x16;
typedef __attribute__((ext_vector_type(4)))  unsigned int uint32x4;

__device__ __forceinline__ ushort f2bf(float f) {
  unsigned u = __builtin_bit_cast(unsigned, f);
  u += 0x7fffu + ((u >> 16) & 1u);   // RNE
  return (ushort)(u >> 16);
}
__device__ __forceinline__ float bf2f(ushort h) {
  unsigned u = ((unsigned)h) << 16;
  return __builtin_bit_cast(float, u);
}
#if __has_builtin(__builtin_amdgcn_exp2f)
#define EXP2F(x) __builtin_amdgcn_exp2f(x)
#else
#define EXP2F(x) exp2f(x)
#endif

// ---------------------------------------------------------------------------
// 1) FUSED front end — RESTORED to the round-7 scalar version (measured as
//    part of the 155.06 µs config). The round-8 float4 rewrite regressed
//    +10 µs (A/B-isolated in round 9): float4-cast stores into local float
//    arrays defeat SROA, and per-lane 144B-stride weight-table loads are a
//    transaction storm.
//    blocks [0,4096):      srln (strided dwconv + LayerNorm -> xsr bf16)
//    blocks [4096,6144):   dwconv 3x3, 8-col segments
//    blocks [6144,6208):   pw_w  f32 -> bf16
//    blocks [6208,6336):   kv_w  f32 -> bf16
//    blocks [6336,6400):   proj_w f32 -> bf16 hi/lo split
__global__ __launch_bounds__(256) void pre_fused(
    const float* __restrict__ x, const float* __restrict__ dw_w,
    const float* __restrict__ dw_b, const float* __restrict__ sr_w,
    const float* __restrict__ ln_g, const float* __restrict__ ln_b,
    const float* __restrict__ pw_w, const float* __restrict__ kv_w,
    const float* __restrict__ proj_w,
    ushort* __restrict__ q1b, ushort* __restrict__ xsr,
    ushort* __restrict__ pwB, ushort* __restrict__ kvB,
    ushort* __restrict__ pjH, ushort* __restrict__ pjL) {
  int bid = blockIdx.x;
  int c = threadIdx.x;
  if (bid < 4096) {
    int b = bid >> 10, m = bid & 1023;
    int my = m >> 5, mx = m & 31;
    const float* xb = x + (size_t)b * NN * CC + c;
    float acc = 0.f;
#pragma unroll
    for (int dy = 0; dy < 3; ++dy) {
      int iy = 2 * my + dy - 1;
      if (iy < 0 || iy >= HH) continue;
#pragma unroll
      for (int dx = 0; dx < 3; ++dx) {
        int ix = 2 * mx + dx - 1;
        if (ix < 0 || ix >= WW) continue;
        acc += xb[(size_t)(iy * WW + ix) * CC] * sr_w[c * 9 + dy * 3 + dx];
      }
    }
    float v1 = acc, v2 = acc * acc;
#pragma unroll
    for (int s = 1; s < 64; s <<= 1) {
      v1 += __shfl_xor(v1, s);
      v2 += __shfl_xor(v2, s);
    }
    __shared__ float r1[4], r2[4];
    int lane = c & 63, wv = c >> 6;
    if (lane == 0) { r1[wv] = v1; r2[wv] = v2; }
    __syncthreads();
    float s1 = r1[0] + r1[1] + r1[2] + r1[3];
    float s2 = r2[0] + r2[1] + r2[2] + r2[3];
    float mu = s1 * (1.f / 256.f);
    float var = s2 * (1.f / 256.f) - mu * mu;
    float yv = (acc - mu) * rsqrtf(var + LN_EPS) * ln_g[c] + ln_b[c];
    xsr[((size_t)b * MM + m) * CC + c] = f2bf(yv);
  } else if (bid < 6144) {
    int id = bid - 4096;                 // 0..2047
    int b = id >> 9, r = id & 511;       // 512 per batch
    int y = r >> 3, seg = r & 7;
    int x0 = seg * 8;
    float wr[9];
#pragma unroll
    for (int i = 0; i < 9; ++i) wr[i] = dw_w[c * 9 + i];
    float bi = dw_b[c];
    const float* xb = x + (size_t)b * NN * CC + c;
    bool okT = (y > 0), okB = (y < 63);
    float a0, a1, a2, b0, b1, b2;
    if (x0 == 0) {
      a0 = a1 = a2 = 0.f;
    } else {
      a0 = okT ? xb[(size_t)((y - 1) * 64 + x0 - 1) * CC] : 0.f;
      a1 = xb[(size_t)(y * 64 + x0 - 1) * CC];
      a2 = okB ? xb[(size_t)((y + 1) * 64 + x0 - 1) * CC] : 0.f;
    }
    b0 = okT ? xb[(size_t)((y - 1) * 64 + x0) * CC] : 0.f;
    b1 = xb[(size_t)(y * 64 + x0) * CC];
    b2 = okB ? xb[(size_t)((y + 1) * 64 + x0) * CC] : 0.f;
    ushort* ob = q1b + ((size_t)b * NN + y * 64) * CC + c;
#pragma unroll 8
    for (int xx = x0; xx < x0 + 8; ++xx) {
      float c0v, c1v, c2v;
      if (xx < 63) {
        c0v = okT ? xb[(size_t)((y - 1) * 64 + xx + 1) * CC] : 0.f;
        c1v = xb[(size_t)(y * 64 + xx + 1) * CC];
        c2v = okB ? xb[(size_t)((y + 1) * 64 + xx + 1) * CC] : 0.f;
      } else {
        c0v = c1v = c2v = 0.f;
      }
      float acc = bi;
      acc += a0 * wr[0] + b0 * wr[1] + c0v * wr[2];
      acc += a1 * wr[3] + b1 * wr[4] + c1v * wr[5];
      acc += a2 * wr[6] + b2 * wr[7] + c2v * wr[8];
      ob[(size_t)xx * CC] = f2bf(acc);
      a0 = b0; a1 = b1; a2 = b2;
      b0 = c0v; b1 = c1v; b2 = c2v;
    }
  } else if (bid < 6208) {
    int i0 = (bid - 6144) * 1024 + c * 4;
    float4 v = *(const float4*)&pw_w[i0];
    ushort tmp[4] = {f2bf(v.x), f2bf(v.y), f2bf(v.z), f2bf(v.w)};
    *(uint2*)&pwB[i0] = *(uint2*)tmp;
  } else if (bid < 6336) {
    int i0 = (bid - 6208) * 1024 + c * 4;
    float4 v = *(const float4*)&kv_w[i0];
    ushort tmp[4] = {f2bf(v.x), f2bf(v.y), f2bf(v.z), f2bf(v.w)};
    *(uint2*)&kvB[i0] = *(uint2*)tmp;
  } else {
    int i0 = (bid - 6336) * 1024 + c * 4;
    float4 v = *(const float4*)&proj_w[i0];
    float vv[4] = {v.x, v.y, v.z, v.w};
    ushort th[4], tl[4];
#pragma unroll
    for (int j = 0; j < 4; ++j) {
      th[j] = f2bf(vv[j]);
      tl[j] = f2bf(vv[j] - bf2f(th[j]));
    }
    *(uint2*)&pjH[i0] = *(uint2*)th;
    *(uint2*)&pjL[i0] = *(uint2*)tl;
  }
}

// ---------------------------------------------------------------------------
// 2) FUSED q-GEMM + kv-GEMM. 64x64 tiles, double-buffered single-barrier,
//    depth-2 register pipeline. (unchanged)
__global__ __launch_bounds__(256) void gemm_qkv(
    const ushort* __restrict__ q1b, const ushort* __restrict__ xsr,
    const ushort* __restrict__ pwB, const float* __restrict__ pw_b,
    const ushort* __restrict__ kvB, const float* __restrict__ kv_b,
    ushort* __restrict__ qB, ushort* __restrict__ kB,
    ushort* __restrict__ vT) {
  __shared__ ushort smem[2][128 * 40];
  int bid = blockIdx.x;
  bool is0 = bid < 1024;
  const ushort* A;
  const ushort* W;
  const float* bias;
  int r0, c0;
  if (is0) {
    A = q1b; W = pwB; bias = pw_b;
    r0 = (bid >> 2) * 64; c0 = (bid & 3) * 64;
  } else {
    int sid = bid - 1024;
    A = xsr; W = kvB; bias = kv_b;
    r0 = (sid >> 3) * 64; c0 = (sid & 7) * 64;
  }
  const bool vmode = (!is0) && (c0 >= 256);

  int t = threadIdx.x;
  int lane = t & 63, w = t >> 6;
  int l31 = lane & 31, half = lane >> 5;
  int wr = w >> 1, wc = w & 1;
  int rowA = t >> 2, kq = (t & 3) * 8;

  f32x16 acc;
#pragma unroll
  for (int i = 0; i < 16; ++i) acc[i] = 0.f;

  short8 ra[2], rw[2];
  auto prefetch = [&](int kc, int s) {
    ra[s] = *(const short8*)&A[(size_t)(r0 + rowA) * 256 + kc + kq];
    rw[s] = *(const short8*)&W[(size_t)(c0 + rowA) * 256 + kc + kq];
  };
  auto store = [&](ushort* buf, int s) {
    *(short8*)&buf[rowA * 40 + kq] = ra[s];
    *(short8*)&buf[64 * 40 + rowA * 40 + kq] = rw[s];
  };

  prefetch(0, 0);
  store(smem[0], 0);
  prefetch(32, 1);
  __syncthreads();
#pragma unroll
  for (int i = 0; i < 8; ++i) {
    ushort* cur = smem[i & 1];
    ushort* nxt = smem[(i & 1) ^ 1];
    if (i < 7) store(nxt, (i + 1) & 1);
    if (i < 6) prefetch((i + 2) * 32, i & 1);
#pragma unroll
    for (int ks = 0; ks < 2; ++ks) {
      short8 af = *(const short8*)&cur[(wr * 32 + l31) * 40 + ks * 16 + half * 8];
      short8 wf = *(const short8*)&cur[64 * 40 + (wc * 32 + l31) * 40 + ks * 16 + half * 8];
      if (vmode)
        acc = __builtin_amdgcn_mfma_f32_32x32x16_bf16(wf, af, acc, 0, 0, 0);
      else
        acc = __builtin_amdgcn_mfma_f32_32x32x16_bf16(af, wf, acc, 0, 0, 0);
    }
    __syncthreads();
  }

#pragma unroll
  for (int i = 0; i < 16; ++i) {
    int rl = (i & 3) + 8 * (i >> 2) + 4 * half;
    if (is0) {
      int r = r0 + wr * 32 + rl;
      int c = c0 + wc * 32 + l31;
      int b = r >> 12, n = r & 4095;
      int h = c >> 5, d = c & 31;
      qB[((size_t)(b * 8 + h) * NN + n) * 32 + d] =
          f2bf((acc[i] + bias[c]) * SLF);
    } else if (!vmode) {
      int r = r0 + wr * 32 + rl;
      int c = c0 + wc * 32 + l31;
      int b = r >> 10, m = r & 1023;
      int h = c >> 5, d = c & 31;
      kB[((size_t)(b * 8 + h) * MM + m) * 32 + d] = f2bf(acc[i] + bias[c]);
    } else {
      int c = c0 + wc * 32 + rl;
      int r = r0 + wr * 32 + l31;
      int b = r >> 10, m = r & 1023;
      int cv = c - 256;
      int h = cv >> 5, d = cv & 31;
      vT[((size_t)(b * 8 + h) * 32 + d) * MM + m] = f2bf(acc[i] + bias[c]);
    }
  }
}

// ---------------------------------------------------------------------------
// 3) MFMA flash attention — NEW: KVBLK=128 (two 64-row halves per LDS
//    buffer, processed sequentially), HALVING the barrier count 16 -> 8.
//    Registers stay flat (st[2]/e[] reused per half; only +2 short8 staging
//    sets). LDS 33.8 KB x 4 blocks = 135 KB < 160 -> occupancy unchanged
//    at 4 blocks/CU. Same MFMA count, same softmax; math bit-identical
//    (two consecutive old chunks merged per barrier).
//    Keeps: depth-2 register pipeline, setprio, T12 in-register P reshape
//    (cvt_pk + permlane32_swap, validated R7), f32-shuffle denominator.
__global__ __launch_bounds__(256, 4) void attn_mfma(
    const ushort* __restrict__ qB, const ushort* __restrict__ kB,
    const ushort* __restrict__ vT, ushort* __restrict__ aH,
    ushort* __restrict__ aL) {
  __shared__ ushort sKa[2][16][264];
  __shared__ ushort sVa[2][16][264];
  int t = threadIdx.x;
  int lane = t & 63, w = t >> 6;
  int l31 = lane & 31, half = lane >> 5;
  int bh = blockIdx.x;
  int b = bh >> 3, h = bh & 7;
  int q0 = blockIdx.y * 128;

  const ushort* qrow = qB + ((size_t)bh * NN + q0 + w * 32 + l31) * 32;
  short8 bq0 = *(const short8*)(qrow + half * 8);
  short8 bq1 = *(const short8*)(qrow + 16 + half * 8);

  const ushort* kbase = kB + (size_t)bh * MM * 32;
  const ushort* vbase = vT + (size_t)bh * 32 * MM;
  int krow = t >> 2, kq = (t & 3) * 8;
  int vd = t >> 3, vmo = (t & 7) * 8;
  int kreg_idx = (krow >> 5) * 4 + (kq >> 4) * 2 + ((kq >> 3) & 1);
  int klane = (krow & 31) * 8;
  int vreg_idx = (vmo >> 4) * 2 + ((vmo >> 3) & 1);
  int vlane = vd * 8;

  // set s holds 128-row chunk c with (c & 1) == s; L/H = lower/upper 64 rows
  short8 krL[2], krH[2], vrL[2], vrH[2];
  krL[0] = *(const short8*)&kbase[(size_t)krow * 32 + kq];
  krH[0] = *(const short8*)&kbase[(size_t)(64 + krow) * 32 + kq];
  vrL[0] = *(const short8*)&vbase[(size_t)vd * MM + vmo];
  vrH[0] = *(const short8*)&vbase[(size_t)vd * MM + 64 + vmo];
  *(short8*)&sKa[0][kreg_idx][klane] = krL[0];
  *(short8*)&sKa[0][8 + kreg_idx][klane] = krH[0];
  *(short8*)&sVa[0][vreg_idx][vlane] = vrL[0];
  *(short8*)&sVa[0][8 + vreg_idx][vlane] = vrH[0];
  krL[1] = *(const short8*)&kbase[(size_t)(128 + krow) * 32 + kq];
  krH[1] = *(const short8*)&kbase[(size_t)(192 + krow) * 32 + kq];
  vrL[1] = *(const short8*)&vbase[(size_t)vd * MM + 128 + vmo];
  vrH[1] = *(const short8*)&vbase[(size_t)vd * MM + 192 + vmo];

  f32x16 o;
#pragma unroll
  for (int i = 0; i < 16; ++i) o[i] = 0.f;
  float psum = 0.f;
  __syncthreads();

  // QK^T -> exp2 -> in-register B-frag reshape -> PV for one 64-row half
  // (off = 0 or 8: which half of the 16-row LDS index space).
  auto doHalf = [&](int cur, int off) {
    f32x16 st[2];
    __builtin_amdgcn_s_setprio(1);
#pragma unroll
    for (int tt = 0; tt < 2; ++tt) {
      short8 a0 = *(const short8*)&sKa[cur][off + tt * 4 + 0 + half][l31 * 8];
      short8 a1 = *(const short8*)&sKa[cur][off + tt * 4 + 2 + half][l31 * 8];
      f32x16 z;
#pragma unroll
      for (int i = 0; i < 16; ++i) z[i] = 0.f;
      z = __builtin_amdgcn_mfma_f32_32x32x16_bf16(a0, bq0, z, 0, 0, 0);
      z = __builtin_amdgcn_mfma_f32_32x32x16_bf16(a1, bq1, z, 0, 0, 0);
      st[tt] = z;
    }
    __builtin_amdgcn_s_setprio(0);

    short8 bp[4];
#pragma unroll
    for (int tt = 0; tt < 2; ++tt) {
      float e[16];
#pragma unroll
      for (int i = 0; i < 16; ++i) e[i] = EXP2F(st[tt][i]);
#pragma unroll
      for (int i = 0; i < 16; i += 4)
        psum += (e[i] + e[i + 1]) + (e[i + 2] + e[i + 3]);
      unsigned pk[8];
#pragma unroll
      for (int j = 0; j < 8; ++j)
        asm("v_cvt_pk_bf16_f32 %0, %1, %2"
            : "=v"(pk[j]) : "v"(e[2 * j]), "v"(e[2 * j + 1]));
#pragma unroll
      for (int kbl = 0; kbl < 2; ++kbl) {
        unsigned w0 = pk[4 * kbl + 0], w2 = pk[4 * kbl + 2];
        unsigned w1 = pk[4 * kbl + 1], w3 = pk[4 * kbl + 3];
        asm("v_permlane32_swap_b32 %0, %1" : "+v"(w0), "+v"(w2));
        asm("v_permlane32_swap_b32 %0, %1" : "+v"(w1), "+v"(w3));
        uint32x4 wbits = {w0, w1, w2, w3};
        bp[2 * tt + kbl] = __builtin_bit_cast(short8, wbits);
      }
    }

    __builtin_amdgcn_s_setprio(1);
#pragma unroll
    for (int kb = 0; kb < 4; ++kb) {
      short8 av = *(const short8*)&sVa[cur][off + kb * 2 + half][l31 * 8];
      o = __builtin_amdgcn_mfma_f32_32x32x16_bf16(av, bp[kb], o, 0, 0, 0);
    }
    __builtin_amdgcn_s_setprio(0);
  };

#pragma unroll 2
  for (int mc = 0; mc < 8; ++mc) {
    int cur = mc & 1, nxt = cur ^ 1;

    doHalf(cur, 0);

    // Store chunk mc+1 (loaded last iter -> vmcnt-free) into buffer nxt;
    // issue loads for chunk mc+2 into the set just freed. Overlaps half B.
    if (mc < 7) {
      *(short8*)&sKa[nxt][kreg_idx][klane] = krL[nxt];
      *(short8*)&sKa[nxt][8 + kreg_idx][klane] = krH[nxt];
      *(short8*)&sVa[nxt][vreg_idx][vlane] = vrL[nxt];
      *(short8*)&sVa[nxt][8 + vreg_idx][vlane] = vrH[nxt];
    }
    if (mc < 6) {
      int m2 = (mc + 2) * 128;
      krL[cur] = *(const short8*)&kbase[(size_t)(m2 + krow) * 32 + kq];
      krH[cur] = *(const short8*)&kbase[(size_t)(m2 + 64 + krow) * 32 + kq];
      vrL[cur] = *(const short8*)&vbase[(size_t)vd * MM + m2 + vmo];
      vrH[cur] = *(const short8*)&vbase[(size_t)vd * MM + m2 + 64 + vmo];
    }

    doHalf(cur, 8);

    __syncthreads();
  }

  float denom = psum + __shfl_xor(psum, 32);
  float inv = 1.f / denom;
  size_t rbase = ((size_t)b * NN + q0 + w * 32 + l31) * 256 + h * 32;
#pragma unroll
  for (int rg = 0; rg < 4; ++rg) {
#pragma unroll
    for (int j = 0; j < 4; ++j) {
      float v = o[rg * 4 + j] * inv;
      ushort hi = f2bf(v);
      ushort lo = f2bf(v - bf2f(hi));
      int d = rg * 8 + half * 4 + j;
      aH[rbase + d] = hi;
      aL[rbase + d] = lo;
    }
  }
}

// ---------------------------------------------------------------------------
// 4) proj GEMM, hi/lo split on A and W, 64x64 tiles, double-buffered
//    single-barrier, depth-2 register pipeline. (unchanged)
__global__ __launch_bounds__(256) void gemm_proj(
    const ushort* __restrict__ A, const ushort* __restrict__ A2,
    const ushort* __restrict__ Whi, const ushort* __restrict__ Wlo,
    const float* __restrict__ bias, float* __restrict__ out) {
  __shared__ ushort smem[2][4 * 64 * 40];
  constexpr int OA = 0, OA2 = 64 * 40, OW = 2 * 64 * 40, OW2 = 3 * 64 * 40;
  int bid = blockIdx.x;
  int r0 = (bid >> 2) * 64, c0 = (bid & 3) * 64;

  int t = threadIdx.x;
  int lane = t & 63, w = t >> 6;
  int l31 = lane & 31, half = lane >> 5;
  int wr = w >> 1, wc = w & 1;
  int rowA = t >> 2, kq = (t & 3) * 8;

  f32x16 acc;
#pragma unroll
  for (int i = 0; i < 16; ++i) acc[i] = 0.f;

  short8 ra[2], ra2[2], rwh[2], rwl[2];
  auto prefetch = [&](int kc, int s) {
    ra[s]  = *(const short8*)&A[(size_t)(r0 + rowA) * 256 + kc + kq];
    ra2[s] = *(const short8*)&A2[(size_t)(r0 + rowA) * 256 + kc + kq];
    rwh[s] = *(const short8*)&Whi[(size_t)(c0 + rowA) * 256 + kc + kq];
    rwl[s] = *(const short8*)&Wlo[(size_t)(c0 + rowA) * 256 + kc + kq];
  };
  auto store = [&](ushort* buf, int s) {
    *(short8*)&buf[OA + rowA * 40 + kq] = ra[s];
    *(short8*)&buf[OA2 + rowA * 40 + kq] = ra2[s];
    *(short8*)&buf[OW + rowA * 40 + kq] = rwh[s];
    *(short8*)&buf[OW2 + rowA * 40 + kq] = rwl[s];
  };

  prefetch(0, 0);
  store(smem[0], 0);
  prefetch(32, 1);
  __syncthreads();
#pragma unroll
  for (int i = 0; i < 8; ++i) {
    ushort* cur = smem[i & 1];
    ushort* nxt = smem[(i & 1) ^ 1];
    if (i < 7) store(nxt, (i + 1) & 1);
    if (i < 6) prefetch((i + 2) * 32, i & 1);
#pragma unroll
    for (int ks = 0; ks < 2; ++ks) {
      int ro = (wr * 32 + l31) * 40 + ks * 16 + half * 8;
      int co = (wc * 32 + l31) * 40 + ks * 16 + half * 8;
      short8 af = *(const short8*)&cur[OA + ro];
      short8 af2 = *(const short8*)&cur[OA2 + ro];
      short8 wf = *(const short8*)&cur[OW + co];
      short8 wf2 = *(const short8*)&cur[OW2 + co];
      acc = __builtin_amdgcn_mfma_f32_32x32x16_bf16(af, wf, acc, 0, 0, 0);
      acc = __builtin_amdgcn_mfma_f32_32x32x16_bf16(af2, wf, acc, 0, 0, 0);
      acc = __builtin_amdgcn_mfma_f32_32x32x16_bf16(af, wf2, acc, 0, 0, 0);
    }
    __syncthreads();
  }

#pragma unroll
  for (int i = 0; i < 16; ++i) {
    int rl = (i & 3) + 8 * (i >> 2) + 4 * half;
    int r = r0 + wr * 32 + rl;
    int c = c0 + wc * 32 + l31;
    out[(size_t)r * 256 + c] = acc[i] + bias[c];
  }
}

// ---------------------------------------------------------------------------
extern "C" void kernel_launch(void* const* d_in, const int* in_sizes, int n_in,
                              void* d_out, int out_size, void* d_ws, size_t ws_size,
                              hipStream_t stream) {
  const float* x      = (const float*)d_in[0];
  const float* dw_w   = (const float*)d_in[1];
  const float* dw_b   = (const float*)d_in[2];
  const float* pw_w   = (const float*)d_in[3];
  const float* pw_b   = (const float*)d_in[4];
  const float* sr_w   = (const float*)d_in[5];
  const float* ln_g   = (const float*)d_in[6];
  const float* ln_b   = (const float*)d_in[7];
  const float* kv_w   = (const float*)d_in[8];
  const float* kv_b   = (const float*)d_in[9];
  const float* proj_w = (const float*)d_in[10];
  const float* proj_b = (const float*)d_in[11];
  float* out = (float*)d_out;

  char* ws = (char*)d_ws;
  ushort* q1b = (ushort*)(ws);                  // 16384x256 bf16  (8 MB)
  ushort* xsr = (ushort*)(ws + (8u << 20));     // 4096x256        (2 MB)
  ushort* qB  = (ushort*)(ws + (16u << 20));    // 32x4096x32      (8 MB)
  ushort* kBp = (ushort*)(ws + (24u << 20));    // 32x1024x32      (2 MB)
  ushort* vTp = (ushort*)(ws + (26u << 20));    // 32x32x1024      (2 MB)
  ushort* aH  = (ushort*)(ws + (28u << 20));    // 16384x256       (8 MB)
  ushort* aL  = (ushort*)(ws + (36u << 20));    // 16384x256       (8 MB)
  ushort* pwB = (ushort*)(ws + (44u << 20));                 // 128 KB
  ushort* kvB = (ushort*)(ws + (44u << 20) + (512u << 10));  // 256 KB
  ushort* pjH = (ushort*)(ws + (45u << 20));                 // 128 KB
  ushort* pjL = (ushort*)(ws + (45u << 20) + (512u << 10));  // 128 KB

  pre_fused<<<dim3(6400), 256, 0, stream>>>(x, dw_w, dw_b, sr_w, ln_g, ln_b,
                                            pw_w, kv_w, proj_w,
                                            q1b, xsr, pwB, kvB, pjH, pjL);
  gemm_qkv<<<dim3(1536), 256, 0, stream>>>(q1b, xsr, pwB, pw_b, kvB, kv_b,
                                           qB, kBp, vTp);
  attn_mfma<<<dim3(32, 32), 256, 0, stream>>>(qB, kBp, vTp, aH, aL);
  gemm_proj<<<dim3(1024), 256, 0, stream>>>(aH, aL, pjH, pjL, proj_b, out);
}

// Round 11
// 146.487 us; speedup vs baseline: 1.4370x; 1.4370x over previous
//
#include <hip/hip_runtime.h>
#include <math.h>

#define BB 4
#define HH 64
#define WW 64
#define CC 256
#define NN 4096   // H*W
#define MM 1024   // (H/2)*(W/2)
#define LN_EPS 1e-6f
#define SLF (0.17677669529663687f * 1.4426950408889634f)

typedef __attribute__((ext_vector_type(8)))  short short8;
typedef __attribute__((ext_vector_type(8)))  _Float16 half8;
typedef __attribute__((ext_vector_type(16))) float f32x16;
typedef __attribute__((ext_vector_type(4)))  unsigned int uint32x4;

__device__ __forceinline__ ushort f2bf(float f) {
  unsigned u = __builtin_bit_cast(unsigned, f);
  u += 0x7fffu + ((u >> 16) & 1u);   // RNE
  return (ushort)(u >> 16);
}
__device__ __forceinline__ float bf2f(ushort h) {
  unsigned u = ((unsigned)h) << 16;
  return __builtin_bit_cast(float, u);
}
__device__ __forceinline__ ushort f2h(float f) {
  return __builtin_bit_cast(ushort, (_Float16)f);   // v_cvt_f16_f32, RNE
}
#if __has_builtin(__builtin_amdgcn_exp2f)
#define EXP2F(x) __builtin_amdgcn_exp2f(x)
#else
#define EXP2F(x) exp2f(x)
#endif

// ---------------------------------------------------------------------------
// 1) FUSED front end (round-7 scalar version — the float4 rewrite regressed,
//    A/B-isolated in round 9).
//    blocks [0,4096):      srln (strided dwconv + LayerNorm -> xsr bf16)
//    blocks [4096,6144):   dwconv 3x3, 8-col segments
//    blocks [6144,6208):   pw_w  f32 -> bf16
//    blocks [6208,6336):   kv_w  f32 -> bf16
//    blocks [6336,6400):   proj_w f32 -> fp16 (single buffer; was bf16 hi/lo)
__global__ __launch_bounds__(256) void pre_fused(
    const float* __restrict__ x, const float* __restrict__ dw_w,
    const float* __restrict__ dw_b, const float* __restrict__ sr_w,
    const float* __restrict__ ln_g, const float* __restrict__ ln_b,
    const float* __restrict__ pw_w, const float* __restrict__ kv_w,
    const float* __restrict__ proj_w,
    ushort* __restrict__ q1b, ushort* __restrict__ xsr,
    ushort* __restrict__ pwB, ushort* __restrict__ kvB,
    ushort* __restrict__ pjH) {
  int bid = blockIdx.x;
  int c = threadIdx.x;
  if (bid < 4096) {
    int b = bid >> 10, m = bid & 1023;
    int my = m >> 5, mx = m & 31;
    const float* xb = x + (size_t)b * NN * CC + c;
    float acc = 0.f;
#pragma unroll
    for (int dy = 0; dy < 3; ++dy) {
      int iy = 2 * my + dy - 1;
      if (iy < 0 || iy >= HH) continue;
#pragma unroll
      for (int dx = 0; dx < 3; ++dx) {
        int ix = 2 * mx + dx - 1;
        if (ix < 0 || ix >= WW) continue;
        acc += xb[(size_t)(iy * WW + ix) * CC] * sr_w[c * 9 + dy * 3 + dx];
      }
    }
    float v1 = acc, v2 = acc * acc;
#pragma unroll
    for (int s = 1; s < 64; s <<= 1) {
      v1 += __shfl_xor(v1, s);
      v2 += __shfl_xor(v2, s);
    }
    __shared__ float r1[4], r2[4];
    int lane = c & 63, wv = c >> 6;
    if (lane == 0) { r1[wv] = v1; r2[wv] = v2; }
    __syncthreads();
    float s1 = r1[0] + r1[1] + r1[2] + r1[3];
    float s2 = r2[0] + r2[1] + r2[2] + r2[3];
    float mu = s1 * (1.f / 256.f);
    float var = s2 * (1.f / 256.f) - mu * mu;
    float yv = (acc - mu) * rsqrtf(var + LN_EPS) * ln_g[c] + ln_b[c];
    xsr[((size_t)b * MM + m) * CC + c] = f2bf(yv);
  } else if (bid < 6144) {
    int id = bid - 4096;                 // 0..2047
    int b = id >> 9, r = id & 511;       // 512 per batch
    int y = r >> 3, seg = r & 7;
    int x0 = seg * 8;
    float wr[9];
#pragma unroll
    for (int i = 0; i < 9; ++i) wr[i] = dw_w[c * 9 + i];
    float bi = dw_b[c];
    const float* xb = x + (size_t)b * NN * CC + c;
    bool okT = (y > 0), okB = (y < 63);
    float a0, a1, a2, b0, b1, b2;
    if (x0 == 0) {
      a0 = a1 = a2 = 0.f;
    } else {
      a0 = okT ? xb[(size_t)((y - 1) * 64 + x0 - 1) * CC] : 0.f;
      a1 = xb[(size_t)(y * 64 + x0 - 1) * CC];
      a2 = okB ? xb[(size_t)((y + 1) * 64 + x0 - 1) * CC] : 0.f;
    }
    b0 = okT ? xb[(size_t)((y - 1) * 64 + x0) * CC] : 0.f;
    b1 = xb[(size_t)(y * 64 + x0) * CC];
    b2 = okB ? xb[(size_t)((y + 1) * 64 + x0) * CC] : 0.f;
    ushort* ob = q1b + ((size_t)b * NN + y * 64) * CC + c;
#pragma unroll 8
    for (int xx = x0; xx < x0 + 8; ++xx) {
      float c0v, c1v, c2v;
      if (xx < 63) {
        c0v = okT ? xb[(size_t)((y - 1) * 64 + xx + 1) * CC] : 0.f;
        c1v = xb[(size_t)(y * 64 + xx + 1) * CC];
        c2v = okB ? xb[(size_t)((y + 1) * 64 + xx + 1) * CC] : 0.f;
      } else {
        c0v = c1v = c2v = 0.f;
      }
      float acc = bi;
      acc += a0 * wr[0] + b0 * wr[1] + c0v * wr[2];
      acc += a1 * wr[3] + b1 * wr[4] + c1v * wr[5];
      acc += a2 * wr[6] + b2 * wr[7] + c2v * wr[8];
      ob[(size_t)xx * CC] = f2bf(acc);
      a0 = b0; a1 = b1; a2 = b2;
      b0 = c0v; b1 = c1v; b2 = c2v;
    }
  } else if (bid < 6208) {
    int i0 = (bid - 6144) * 1024 + c * 4;
    float4 v = *(const float4*)&pw_w[i0];
    ushort tmp[4] = {f2bf(v.x), f2bf(v.y), f2bf(v.z), f2bf(v.w)};
    *(uint2*)&pwB[i0] = *(uint2*)tmp;
  } else if (bid < 6336) {
    int i0 = (bid - 6208) * 1024 + c * 4;
    float4 v = *(const float4*)&kv_w[i0];
    ushort tmp[4] = {f2bf(v.x), f2bf(v.y), f2bf(v.z), f2bf(v.w)};
    *(uint2*)&kvB[i0] = *(uint2*)tmp;
  } else {
    // proj_w: f32 -> fp16 single buffer (10 mantissa bits replace the old
    // bf16 hi/lo pair -> gemm_proj needs 1 MFMA instead of 3)
    int i0 = (bid - 6336) * 1024 + c * 4;
    float4 v = *(const float4*)&proj_w[i0];
    ushort th[4] = {f2h(v.x), f2h(v.y), f2h(v.z), f2h(v.w)};
    *(uint2*)&pjH[i0] = *(uint2*)th;
  }
}

// ---------------------------------------------------------------------------
// 2) FUSED q-GEMM + kv-GEMM. 64x64 tiles, double-buffered single-barrier,
//    depth-2 register pipeline. (unchanged, R7)
__global__ __launch_bounds__(256) void gemm_qkv(
    const ushort* __restrict__ q1b, const ushort* __restrict__ xsr,
    const ushort* __restrict__ pwB, const float* __restrict__ pw_b,
    const ushort* __restrict__ kvB, const float* __restrict__ kv_b,
    ushort* __restrict__ qB, ushort* __restrict__ kB,
    ushort* __restrict__ vT) {
  __shared__ ushort smem[2][128 * 40];
  int bid = blockIdx.x;
  bool is0 = bid < 1024;
  const ushort* A;
  const ushort* W;
  const float* bias;
  int r0, c0;
  if (is0) {
    A = q1b; W = pwB; bias = pw_b;
    r0 = (bid >> 2) * 64; c0 = (bid & 3) * 64;
  } else {
    int sid = bid - 1024;
    A = xsr; W = kvB; bias = kv_b;
    r0 = (sid >> 3) * 64; c0 = (sid & 7) * 64;
  }
  const bool vmode = (!is0) && (c0 >= 256);

  int t = threadIdx.x;
  int lane = t & 63, w = t >> 6;
  int l31 = lane & 31, half = lane >> 5;
  int wr = w >> 1, wc = w & 1;
  int rowA = t >> 2, kq = (t & 3) * 8;

  f32x16 acc;
#pragma unroll
  for (int i = 0; i < 16; ++i) acc[i] = 0.f;

  short8 ra[2], rw[2];
  auto prefetch = [&](int kc, int s) {
    ra[s] = *(const short8*)&A[(size_t)(r0 + rowA) * 256 + kc + kq];
    rw[s] = *(const short8*)&W[(size_t)(c0 + rowA) * 256 + kc + kq];
  };
  auto store = [&](ushort* buf, int s) {
    *(short8*)&buf[rowA * 40 + kq] = ra[s];
    *(short8*)&buf[64 * 40 + rowA * 40 + kq] = rw[s];
  };

  prefetch(0, 0);
  store(smem[0], 0);
  prefetch(32, 1);
  __syncthreads();
#pragma unroll
  for (int i = 0; i < 8; ++i) {
    ushort* cur = smem[i & 1];
    ushort* nxt = smem[(i & 1) ^ 1];
    if (i < 7) store(nxt, (i + 1) & 1);
    if (i < 6) prefetch((i + 2) * 32, i & 1);
#pragma unroll
    for (int ks = 0; ks < 2; ++ks) {
      short8 af = *(const short8*)&cur[(wr * 32 + l31) * 40 + ks * 16 + half * 8];
      short8 wf = *(const short8*)&cur[64 * 40 + (wc * 32 + l31) * 40 + ks * 16 + half * 8];
      if (vmode)
        acc = __builtin_amdgcn_mfma_f32_32x32x16_bf16(wf, af, acc, 0, 0, 0);
      else
        acc = __builtin_amdgcn_mfma_f32_32x32x16_bf16(af, wf, acc, 0, 0, 0);
    }
    __syncthreads();
  }

#pragma unroll
  for (int i = 0; i < 16; ++i) {
    int rl = (i & 3) + 8 * (i >> 2) + 4 * half;
    if (is0) {
      int r = r0 + wr * 32 + rl;
      int c = c0 + wc * 32 + l31;
      int b = r >> 12, n = r & 4095;
      int h = c >> 5, d = c & 31;
      qB[((size_t)(b * 8 + h) * NN + n) * 32 + d] =
          f2bf((acc[i] + bias[c]) * SLF);
    } else if (!vmode) {
      int r = r0 + wr * 32 + rl;
      int c = c0 + wc * 32 + l31;
      int b = r >> 10, m = r & 1023;
      int h = c >> 5, d = c & 31;
      kB[((size_t)(b * 8 + h) * MM + m) * 32 + d] = f2bf(acc[i] + bias[c]);
    } else {
      int c = c0 + wc * 32 + rl;
      int r = r0 + wr * 32 + l31;
      int b = r >> 10, m = r & 1023;
      int cv = c - 256;
      int h = cv >> 5, d = cv & 31;
      vT[((size_t)(b * 8 + h) * 32 + d) * MM + m] = f2bf(acc[i] + bias[c]);
    }
  }
}

// ---------------------------------------------------------------------------
// 3) MFMA flash attention — EXACT R7 structure (validated, best measured;
//    KVBLK=64, launch_bounds(256,4); R10's KVBLK=128 added +32 VGPR of
//    staging state, overflowed the 128-VGPR budget and spilled 265 MB to
//    scratch). Only change vs R7: epilogue writes O as ONE fp16 value
//    (was bf16 hi/lo pair) — fewer VALU + half the stores.
__global__ __launch_bounds__(256, 4) void attn_mfma(
    const ushort* __restrict__ qB, const ushort* __restrict__ kB,
    const ushort* __restrict__ vT, ushort* __restrict__ aH) {
  __shared__ ushort sKa[2][8][264];
  __shared__ ushort sVa[2][8][264];
  int t = threadIdx.x;
  int lane = t & 63, w = t >> 6;
  int l31 = lane & 31, half = lane >> 5;
  int bh = blockIdx.x;
  int b = bh >> 3, h = bh & 7;
  int q0 = blockIdx.y * 128;

  const ushort* qrow = qB + ((size_t)bh * NN + q0 + w * 32 + l31) * 32;
  short8 bq0 = *(const short8*)(qrow + half * 8);
  short8 bq1 = *(const short8*)(qrow + 16 + half * 8);

  const ushort* kbase = kB + (size_t)bh * MM * 32;
  const ushort* vbase = vT + (size_t)bh * 32 * MM;
  int krow = t >> 2, kq = (t & 3) * 8;
  int vd = t >> 3, vmo = (t & 7) * 8;
  int kreg_idx = (krow >> 5) * 4 + (kq >> 4) * 2 + ((kq >> 3) & 1);
  int klane = (krow & 31) * 8;
  int vreg_idx = (vmo >> 4) * 2 + ((vmo >> 3) & 1);
  int vlane = vd * 8;

  // set s holds chunk c with (c & 1) == s
  short8 kr[2], vr[2];
  kr[0] = *(const short8*)&kbase[(size_t)krow * 32 + kq];
  vr[0] = *(const short8*)&vbase[(size_t)vd * MM + vmo];
  kr[1] = *(const short8*)&kbase[(size_t)(64 + krow) * 32 + kq];
  vr[1] = *(const short8*)&vbase[(size_t)vd * MM + 64 + vmo];
  *(short8*)&sKa[0][kreg_idx][klane] = kr[0];
  *(short8*)&sVa[0][vreg_idx][vlane] = vr[0];

  f32x16 o;
#pragma unroll
  for (int i = 0; i < 16; ++i) o[i] = 0.f;
  float psum = 0.f;
  __syncthreads();

#pragma unroll 2
  for (int mc = 0; mc < 16; ++mc) {
    int cur = mc & 1, nxt = cur ^ 1;

    // S^T = K·Q^T : two 32x32 tiles
    f32x16 st[2];
    __builtin_amdgcn_s_setprio(1);
#pragma unroll
    for (int tt = 0; tt < 2; ++tt) {
      short8 a0 = *(const short8*)&sKa[cur][tt * 4 + 0 + half][l31 * 8];
      short8 a1 = *(const short8*)&sKa[cur][tt * 4 + 2 + half][l31 * 8];
      f32x16 z;
#pragma unroll
      for (int i = 0; i < 16; ++i) z[i] = 0.f;
      z = __builtin_amdgcn_mfma_f32_32x32x16_bf16(a0, bq0, z, 0, 0, 0);
      z = __builtin_amdgcn_mfma_f32_32x32x16_bf16(a1, bq1, z, 0, 0, 0);
      st[tt] = z;
    }
    __builtin_amdgcn_s_setprio(0);

    // Store chunk mc+1 (loaded last iter -> vmcnt-free) into buffer nxt;
    // issue loads for chunk mc+2 into the set just freed.
    if (mc < 15) {
      *(short8*)&sKa[nxt][kreg_idx][klane] = kr[nxt];
      *(short8*)&sVa[nxt][vreg_idx][vlane] = vr[nxt];
    }
    if (mc < 14) {
      int m2 = (mc + 2) * 64;
      kr[cur] = *(const short8*)&kbase[(size_t)(m2 + krow) * 32 + kq];
      vr[cur] = *(const short8*)&vbase[(size_t)vd * MM + m2 + vmo];
    }

    // P = exp2(st) -> bf16 B-frags in registers (cvt_pk + permlane swaps);
    // f32 row-sum folded in for the softmax denominator.
    short8 bp[4];
#pragma unroll
    for (int tt = 0; tt < 2; ++tt) {
      float e[16];
#pragma unroll
      for (int i = 0; i < 16; ++i) e[i] = EXP2F(st[tt][i]);
#pragma unroll
      for (int i = 0; i < 16; i += 4)
        psum += (e[i] + e[i + 1]) + (e[i + 2] + e[i + 3]);
      unsigned pk[8];
#pragma unroll
      for (int j = 0; j < 8; ++j)
        asm("v_cvt_pk_bf16_f32 %0, %1, %2"
            : "=v"(pk[j]) : "v"(e[2 * j]), "v"(e[2 * j + 1]));
#pragma unroll
      for (int kbl = 0; kbl < 2; ++kbl) {
        unsigned w0 = pk[4 * kbl + 0], w2 = pk[4 * kbl + 2];
        unsigned w1 = pk[4 * kbl + 1], w3 = pk[4 * kbl + 3];
        asm("v_permlane32_swap_b32 %0, %1" : "+v"(w0), "+v"(w2));
        asm("v_permlane32_swap_b32 %0, %1" : "+v"(w1), "+v"(w3));
        uint32x4 wbits = {w0, w1, w2, w3};
        bp[2 * tt + kbl] = __builtin_bit_cast(short8, wbits);
      }
    }

    // O^T += V^T·P
    __builtin_amdgcn_s_setprio(1);
#pragma unroll
    for (int kb = 0; kb < 4; ++kb) {
      short8 av = *(const short8*)&sVa[cur][kb * 2 + half][l31 * 8];
      o = __builtin_amdgcn_mfma_f32_32x32x16_bf16(av, bp[kb], o, 0, 0, 0);
    }
    __builtin_amdgcn_s_setprio(0);

    __syncthreads();
  }

  float denom = psum + __shfl_xor(psum, 32);
  float inv = 1.f / denom;
  size_t rbase = ((size_t)b * NN + q0 + w * 32 + l31) * 256 + h * 32;
#pragma unroll
  for (int rg = 0; rg < 4; ++rg) {
#pragma unroll
    for (int j = 0; j < 4; ++j) {
      float v = o[rg * 4 + j] * inv;
      int d = rg * 8 + half * 4 + j;
      aH[rbase + d] = f2h(v);
    }
  }
}

// ---------------------------------------------------------------------------
// 4) proj GEMM — fp16 single-precision-path (was bf16 hi/lo x3 MFMA):
//    A = attention output in fp16, W = proj_w in fp16. 10 mantissa bits
//    replace the hi/lo trick -> 1 MFMA per k-slice (was 3), 2 staging
//    streams (was 4), half the LDS. Same 64x64 tiles, double-buffered
//    single-barrier, depth-2 register pipeline.
__global__ __launch_bounds__(256) void gemm_proj(
    const ushort* __restrict__ A, const ushort* __restrict__ Whi,
    const float* __restrict__ bias, float* __restrict__ out) {
  __shared__ ushort smem[2][2 * 64 * 40];
  constexpr int OA = 0, OW = 64 * 40;
  int bid = blockIdx.x;
  int r0 = (bid >> 2) * 64, c0 = (bid & 3) * 64;

  int t = threadIdx.x;
  int lane = t & 63, w = t >> 6;
  int l31 = lane & 31, half = lane >> 5;
  int wr = w >> 1, wc = w & 1;
  int rowA = t >> 2, kq = (t & 3) * 8;

  f32x16 acc;
#pragma unroll
  for (int i = 0; i < 16; ++i) acc[i] = 0.f;

  short8 ra[2], rwh[2];
  auto prefetch = [&](int kc, int s) {
    ra[s]  = *(const short8*)&A[(size_t)(r0 + rowA) * 256 + kc + kq];
    rwh[s] = *(const short8*)&Whi[(size_t)(c0 + rowA) * 256 + kc + kq];
  };
  auto store = [&](ushort* buf, int s) {
    *(short8*)&buf[OA + rowA * 40 + kq] = ra[s];
    *(short8*)&buf[OW + rowA * 40 + kq] = rwh[s];
  };

  prefetch(0, 0);
  store(smem[0], 0);
  prefetch(32, 1);
  __syncthreads();
#pragma unroll
  for (int i = 0; i < 8; ++i) {
    ushort* cur = smem[i & 1];
    ushort* nxt = smem[(i & 1) ^ 1];
    if (i < 7) store(nxt, (i + 1) & 1);
    if (i < 6) prefetch((i + 2) * 32, i & 1);
#pragma unroll
    for (int ks = 0; ks < 2; ++ks) {
      int ro = (wr * 32 + l31) * 40 + ks * 16 + half * 8;
      int co = (wc * 32 + l31) * 40 + ks * 16 + half * 8;
      half8 af = __builtin_bit_cast(half8, *(const short8*)&cur[OA + ro]);
      half8 wf = __builtin_bit_cast(half8, *(const short8*)&cur[OW + co]);
      acc = __builtin_amdgcn_mfma_f32_32x32x16_f16(af, wf, acc, 0, 0, 0);
    }
    __syncthreads();
  }

#pragma unroll
  for (int i = 0; i < 16; ++i) {
    int rl = (i & 3) + 8 * (i >> 2) + 4 * half;
    int r = r0 + wr * 32 + rl;
    int c = c0 + wc * 32 + l31;
    out[(size_t)r * 256 + c] = acc[i] + bias[c];
  }
}

// ---------------------------------------------------------------------------
extern "C" void kernel_launch(void* const* d_in, const int* in_sizes, int n_in,
                              void* d_out, int out_size, void* d_ws, size_t ws_size,
                              hipStream_t stream) {
  const float* x      = (const float*)d_in[0];
  const float* dw_w   = (const float*)d_in[1];
  const float* dw_b   = (const float*)d_in[2];
  const float* pw_w   = (const float*)d_in[3];
  const float* pw_b   = (const float*)d_in[4];
  const float* sr_w   = (const float*)d_in[5];
  const float* ln_g   = (const float*)d_in[6];
  const float* ln_b   = (const float*)d_in[7];
  const float* kv_w   = (const float*)d_in[8];
  const float* kv_b   = (const float*)d_in[9];
  const float* proj_w = (const float*)d_in[10];
  const float* proj_b = (const float*)d_in[11];
  float* out = (float*)d_out;

  char* ws = (char*)d_ws;
  ushort* q1b = (ushort*)(ws);                  // 16384x256 bf16  (8 MB)
  ushort* xsr = (ushort*)(ws + (8u << 20));     // 4096x256        (2 MB)
  ushort* qB  = (ushort*)(ws + (16u << 20));    // 32x4096x32      (8 MB)
  ushort* kBp = (ushort*)(ws + (24u << 20));    // 32x1024x32      (2 MB)
  ushort* vTp = (ushort*)(ws + (26u << 20));    // 32x32x1024      (2 MB)
  ushort* aH  = (ushort*)(ws + (28u << 20));    // 16384x256 fp16  (8 MB)
  ushort* pwB = (ushort*)(ws + (44u << 20));                 // 128 KB
  ushort* kvB = (ushort*)(ws + (44u << 20) + (512u << 10));  // 256 KB
  ushort* pjH = (ushort*)(ws + (45u << 20));                 // 128 KB fp16

  pre_fused<<<dim3(6400), 256, 0, stream>>>(x, dw_w, dw_b, sr_w, ln_g, ln_b,
                                            pw_w, kv_w, proj_w,
                                            q1b, xsr, pwB, kvB, pjH);
  gemm_qkv<<<dim3(1536), 256, 0, stream>>>(q1b, xsr, pwB, pw_b, kvB, kv_b,
                                           qB, kBp, vTp);
  attn_mfma<<<dim3(32, 32), 256, 0, stream>>>(qB, kBp, vTp, aH);
  gemm_proj<<<dim3(1024), 256, 0, stream>>>(aH, pjH, proj_b, out);
}

// Round 12
// 145.913 us; speedup vs baseline: 1.4427x; 1.0039x over previous
//
#include <hip/hip_runtime.h>
#include <math.h>

#define BB 4
#define HH 64
#define WW 64
#define CC 256
#define NN 4096   // H*W
#define MM 1024   // (H/2)*(W/2)
#define LN_EPS 1e-6f
#define SLF (0.17677669529663687f * 1.4426950408889634f)

typedef __attribute__((ext_vector_type(8)))  short short8;
typedef __attribute__((ext_vector_type(8)))  _Float16 half8;
typedef __attribute__((ext_vector_type(16))) float f32x16;
typedef __attribute__((ext_vector_type(4)))  unsigned int uint32x4;

__device__ __forceinline__ ushort f2bf(float f) {
  unsigned u = __builtin_bit_cast(unsigned, f);
  u += 0x7fffu + ((u >> 16) & 1u);   // RNE
  return (ushort)(u >> 16);
}
__device__ __forceinline__ float bf2f(ushort h) {
  unsigned u = ((unsigned)h) << 16;
  return __builtin_bit_cast(float, u);
}
__device__ __forceinline__ ushort f2h(float f) {
  return __builtin_bit_cast(ushort, (_Float16)f);   // v_cvt_f16_f32, RNE
}
#if __has_builtin(__builtin_amdgcn_exp2f)
#define EXP2F(x) __builtin_amdgcn_exp2f(x)
#else
#define EXP2F(x) exp2f(x)
#endif

// ---------------------------------------------------------------------------
// 1) FUSED front end (round-7 scalar version; R8's vectorized rewrite was a
//    TLP collapse — 4x fewer waves — not an SROA issue as first thought).
//    blocks [0,4096):      srln (strided dwconv + LayerNorm -> xsr bf16)
//    blocks [4096,6144):   dwconv 3x3, 8-col segments
//    blocks [6144,6208):   pw_w  f32 -> bf16
//    blocks [6208,6336):   kv_w  f32 -> bf16
//    blocks [6336,6400):   proj_w f32 -> fp16
__global__ __launch_bounds__(256) void pre_fused(
    const float* __restrict__ x, const float* __restrict__ dw_w,
    const float* __restrict__ dw_b, const float* __restrict__ sr_w,
    const float* __restrict__ ln_g, const float* __restrict__ ln_b,
    const float* __restrict__ pw_w, const float* __restrict__ kv_w,
    const float* __restrict__ proj_w,
    ushort* __restrict__ q1b, ushort* __restrict__ xsr,
    ushort* __restrict__ pwB, ushort* __restrict__ kvB,
    ushort* __restrict__ pjH) {
  int bid = blockIdx.x;
  int c = threadIdx.x;
  if (bid < 4096) {
    int b = bid >> 10, m = bid & 1023;
    int my = m >> 5, mx = m & 31;
    const float* xb = x + (size_t)b * NN * CC + c;
    float acc = 0.f;
#pragma unroll
    for (int dy = 0; dy < 3; ++dy) {
      int iy = 2 * my + dy - 1;
      if (iy < 0 || iy >= HH) continue;
#pragma unroll
      for (int dx = 0; dx < 3; ++dx) {
        int ix = 2 * mx + dx - 1;
        if (ix < 0 || ix >= WW) continue;
        acc += xb[(size_t)(iy * WW + ix) * CC] * sr_w[c * 9 + dy * 3 + dx];
      }
    }
    float v1 = acc, v2 = acc * acc;
#pragma unroll
    for (int s = 1; s < 64; s <<= 1) {
      v1 += __shfl_xor(v1, s);
      v2 += __shfl_xor(v2, s);
    }
    __shared__ float r1[4], r2[4];
    int lane = c & 63, wv = c >> 6;
    if (lane == 0) { r1[wv] = v1; r2[wv] = v2; }
    __syncthreads();
    float s1 = r1[0] + r1[1] + r1[2] + r1[3];
    float s2 = r2[0] + r2[1] + r2[2] + r2[3];
    float mu = s1 * (1.f / 256.f);
    float var = s2 * (1.f / 256.f) - mu * mu;
    float yv = (acc - mu) * rsqrtf(var + LN_EPS) * ln_g[c] + ln_b[c];
    xsr[((size_t)b * MM + m) * CC + c] = f2bf(yv);
  } else if (bid < 6144) {
    int id = bid - 4096;                 // 0..2047
    int b = id >> 9, r = id & 511;       // 512 per batch
    int y = r >> 3, seg = r & 7;
    int x0 = seg * 8;
    float wr[9];
#pragma unroll
    for (int i = 0; i < 9; ++i) wr[i] = dw_w[c * 9 + i];
    float bi = dw_b[c];
    const float* xb = x + (size_t)b * NN * CC + c;
    bool okT = (y > 0), okB = (y < 63);
    float a0, a1, a2, b0, b1, b2;
    if (x0 == 0) {
      a0 = a1 = a2 = 0.f;
    } else {
      a0 = okT ? xb[(size_t)((y - 1) * 64 + x0 - 1) * CC] : 0.f;
      a1 = xb[(size_t)(y * 64 + x0 - 1) * CC];
      a2 = okB ? xb[(size_t)((y + 1) * 64 + x0 - 1) * CC] : 0.f;
    }
    b0 = okT ? xb[(size_t)((y - 1) * 64 + x0) * CC] : 0.f;
    b1 = xb[(size_t)(y * 64 + x0) * CC];
    b2 = okB ? xb[(size_t)((y + 1) * 64 + x0) * CC] : 0.f;
    ushort* ob = q1b + ((size_t)b * NN + y * 64) * CC + c;
#pragma unroll 8
    for (int xx = x0; xx < x0 + 8; ++xx) {
      float c0v, c1v, c2v;
      if (xx < 63) {
        c0v = okT ? xb[(size_t)((y - 1) * 64 + xx + 1) * CC] : 0.f;
        c1v = xb[(size_t)(y * 64 + xx + 1) * CC];
        c2v = okB ? xb[(size_t)((y + 1) * 64 + xx + 1) * CC] : 0.f;
      } else {
        c0v = c1v = c2v = 0.f;
      }
      float acc = bi;
      acc += a0 * wr[0] + b0 * wr[1] + c0v * wr[2];
      acc += a1 * wr[3] + b1 * wr[4] + c1v * wr[5];
      acc += a2 * wr[6] + b2 * wr[7] + c2v * wr[8];
      ob[(size_t)xx * CC] = f2bf(acc);
      a0 = b0; a1 = b1; a2 = b2;
      b0 = c0v; b1 = c1v; b2 = c2v;
    }
  } else if (bid < 6208) {
    int i0 = (bid - 6144) * 1024 + c * 4;
    float4 v = *(const float4*)&pw_w[i0];
    ushort tmp[4] = {f2bf(v.x), f2bf(v.y), f2bf(v.z), f2bf(v.w)};
    *(uint2*)&pwB[i0] = *(uint2*)tmp;
  } else if (bid < 6336) {
    int i0 = (bid - 6208) * 1024 + c * 4;
    float4 v = *(const float4*)&kv_w[i0];
    ushort tmp[4] = {f2bf(v.x), f2bf(v.y), f2bf(v.z), f2bf(v.w)};
    *(uint2*)&kvB[i0] = *(uint2*)tmp;
  } else {
    int i0 = (bid - 6336) * 1024 + c * 4;
    float4 v = *(const float4*)&proj_w[i0];
    ushort th[4] = {f2h(v.x), f2h(v.y), f2h(v.z), f2h(v.w)};
    *(uint2*)&pjH[i0] = *(uint2*)th;
  }
}

// ---------------------------------------------------------------------------
// 2) FUSED q-GEMM + kv-GEMM. 64x64 tiles, double-buffered single-barrier,
//    depth-2 register pipeline. (unchanged, R7/R11)
__global__ __launch_bounds__(256) void gemm_qkv(
    const ushort* __restrict__ q1b, const ushort* __restrict__ xsr,
    const ushort* __restrict__ pwB, const float* __restrict__ pw_b,
    const ushort* __restrict__ kvB, const float* __restrict__ kv_b,
    ushort* __restrict__ qB, ushort* __restrict__ kB,
    ushort* __restrict__ vT) {
  __shared__ ushort smem[2][128 * 40];
  int bid = blockIdx.x;
  bool is0 = bid < 1024;
  const ushort* A;
  const ushort* W;
  const float* bias;
  int r0, c0;
  if (is0) {
    A = q1b; W = pwB; bias = pw_b;
    r0 = (bid >> 2) * 64; c0 = (bid & 3) * 64;
  } else {
    int sid = bid - 1024;
    A = xsr; W = kvB; bias = kv_b;
    r0 = (sid >> 3) * 64; c0 = (sid & 7) * 64;
  }
  const bool vmode = (!is0) && (c0 >= 256);

  int t = threadIdx.x;
  int lane = t & 63, w = t >> 6;
  int l31 = lane & 31, half = lane >> 5;
  int wr = w >> 1, wc = w & 1;
  int rowA = t >> 2, kq = (t & 3) * 8;

  f32x16 acc;
#pragma unroll
  for (int i = 0; i < 16; ++i) acc[i] = 0.f;

  short8 ra[2], rw[2];
  auto prefetch = [&](int kc, int s) {
    ra[s] = *(const short8*)&A[(size_t)(r0 + rowA) * 256 + kc + kq];
    rw[s] = *(const short8*)&W[(size_t)(c0 + rowA) * 256 + kc + kq];
  };
  auto store = [&](ushort* buf, int s) {
    *(short8*)&buf[rowA * 40 + kq] = ra[s];
    *(short8*)&buf[64 * 40 + rowA * 40 + kq] = rw[s];
  };

  prefetch(0, 0);
  store(smem[0], 0);
  prefetch(32, 1);
  __syncthreads();
#pragma unroll
  for (int i = 0; i < 8; ++i) {
    ushort* cur = smem[i & 1];
    ushort* nxt = smem[(i & 1) ^ 1];
    if (i < 7) store(nxt, (i + 1) & 1);
    if (i < 6) prefetch((i + 2) * 32, i & 1);
#pragma unroll
    for (int ks = 0; ks < 2; ++ks) {
      short8 af = *(const short8*)&cur[(wr * 32 + l31) * 40 + ks * 16 + half * 8];
      short8 wf = *(const short8*)&cur[64 * 40 + (wc * 32 + l31) * 40 + ks * 16 + half * 8];
      if (vmode)
        acc = __builtin_amdgcn_mfma_f32_32x32x16_bf16(wf, af, acc, 0, 0, 0);
      else
        acc = __builtin_amdgcn_mfma_f32_32x32x16_bf16(af, wf, acc, 0, 0, 0);
    }
    __syncthreads();
  }

#pragma unroll
  for (int i = 0; i < 16; ++i) {
    int rl = (i & 3) + 8 * (i >> 2) + 4 * half;
    if (is0) {
      int r = r0 + wr * 32 + rl;
      int c = c0 + wc * 32 + l31;
      int b = r >> 12, n = r & 4095;
      int h = c >> 5, d = c & 31;
      qB[((size_t)(b * 8 + h) * NN + n) * 32 + d] =
          f2bf((acc[i] + bias[c]) * SLF);
    } else if (!vmode) {
      int r = r0 + wr * 32 + rl;
      int c = c0 + wc * 32 + l31;
      int b = r >> 10, m = r & 1023;
      int h = c >> 5, d = c & 31;
      kB[((size_t)(b * 8 + h) * MM + m) * 32 + d] = f2bf(acc[i] + bias[c]);
    } else {
      int c = c0 + wc * 32 + rl;
      int r = r0 + wr * 32 + l31;
      int b = r >> 10, m = r & 1023;
      int cv = c - 256;
      int h = cv >> 5, d = cv & 31;
      vT[((size_t)(b * 8 + h) * 32 + d) * MM + m] = f2bf(acc[i] + bias[c]);
    }
  }
}

// ---------------------------------------------------------------------------
// 3) MFMA flash attention — R11 core (validated), two scheduling changes:
//    (a) GRID SWAP: blockIdx.x = q-chunk (fast), blockIdx.y = bh. The
//        co-resident block set now shares few K/V sets: per-XCD K/V L2
//        footprint drops 4 MB -> ~1 MB (was thrashing the whole XCD L2).
//    (b) EPILOGUE LDS TRANSPOSE: lanes hold different q-ROWS, so direct
//        fp16 stores scattered 64 lanes over 32 lines at 512B stride
//        (~32x transaction amplification on 8 MB). Stage the 32x32 wave
//        tile in a dedicated 9 KB LDS buffer (post-loop, no main-loop
//        register change; 26 KB/block x 4 = 104 KB keeps occupancy) and
//        write 4x fully-coalesced 8B/lane instructions.
__global__ __launch_bounds__(256, 4) void attn_mfma(
    const ushort* __restrict__ qB, const ushort* __restrict__ kB,
    const ushort* __restrict__ vT, ushort* __restrict__ aH) {
  __shared__ ushort sKa[2][8][264];
  __shared__ ushort sVa[2][8][264];
  __shared__ ushort tb[4][32][36];   // epilogue transpose, per-wave region
  int t = threadIdx.x;
  int lane = t & 63, w = t >> 6;
  int l31 = lane & 31, half = lane >> 5;
  int bh = blockIdx.y;                      // (a) swapped
  int b = bh >> 3, h = bh & 7;
  int q0 = blockIdx.x * 128;                // (a) swapped

  const ushort* qrow = qB + ((size_t)bh * NN + q0 + w * 32 + l31) * 32;
  short8 bq0 = *(const short8*)(qrow + half * 8);
  short8 bq1 = *(const short8*)(qrow + 16 + half * 8);

  const ushort* kbase = kB + (size_t)bh * MM * 32;
  const ushort* vbase = vT + (size_t)bh * 32 * MM;
  int krow = t >> 2, kq = (t & 3) * 8;
  int vd = t >> 3, vmo = (t & 7) * 8;
  int kreg_idx = (krow >> 5) * 4 + (kq >> 4) * 2 + ((kq >> 3) & 1);
  int klane = (krow & 31) * 8;
  int vreg_idx = (vmo >> 4) * 2 + ((vmo >> 3) & 1);
  int vlane = vd * 8;

  // set s holds chunk c with (c & 1) == s
  short8 kr[2], vr[2];
  kr[0] = *(const short8*)&kbase[(size_t)krow * 32 + kq];
  vr[0] = *(const short8*)&vbase[(size_t)vd * MM + vmo];
  kr[1] = *(const short8*)&kbase[(size_t)(64 + krow) * 32 + kq];
  vr[1] = *(const short8*)&vbase[(size_t)vd * MM + 64 + vmo];
  *(short8*)&sKa[0][kreg_idx][klane] = kr[0];
  *(short8*)&sVa[0][vreg_idx][vlane] = vr[0];

  f32x16 o;
#pragma unroll
  for (int i = 0; i < 16; ++i) o[i] = 0.f;
  float psum = 0.f;
  __syncthreads();

#pragma unroll 2
  for (int mc = 0; mc < 16; ++mc) {
    int cur = mc & 1, nxt = cur ^ 1;

    // S^T = K·Q^T : two 32x32 tiles
    f32x16 st[2];
    __builtin_amdgcn_s_setprio(1);
#pragma unroll
    for (int tt = 0; tt < 2; ++tt) {
      short8 a0 = *(const short8*)&sKa[cur][tt * 4 + 0 + half][l31 * 8];
      short8 a1 = *(const short8*)&sKa[cur][tt * 4 + 2 + half][l31 * 8];
      f32x16 z;
#pragma unroll
      for (int i = 0; i < 16; ++i) z[i] = 0.f;
      z = __builtin_amdgcn_mfma_f32_32x32x16_bf16(a0, bq0, z, 0, 0, 0);
      z = __builtin_amdgcn_mfma_f32_32x32x16_bf16(a1, bq1, z, 0, 0, 0);
      st[tt] = z;
    }
    __builtin_amdgcn_s_setprio(0);

    // Store chunk mc+1 (loaded last iter -> vmcnt-free) into buffer nxt;
    // issue loads for chunk mc+2 into the set just freed.
    if (mc < 15) {
      *(short8*)&sKa[nxt][kreg_idx][klane] = kr[nxt];
      *(short8*)&sVa[nxt][vreg_idx][vlane] = vr[nxt];
    }
    if (mc < 14) {
      int m2 = (mc + 2) * 64;
      kr[cur] = *(const short8*)&kbase[(size_t)(m2 + krow) * 32 + kq];
      vr[cur] = *(const short8*)&vbase[(size_t)vd * MM + m2 + vmo];
    }

    // P = exp2(st) -> bf16 B-frags in registers (cvt_pk + permlane swaps);
    // f32 row-sum folded in for the softmax denominator.
    short8 bp[4];
#pragma unroll
    for (int tt = 0; tt < 2; ++tt) {
      float e[16];
#pragma unroll
      for (int i = 0; i < 16; ++i) e[i] = EXP2F(st[tt][i]);
#pragma unroll
      for (int i = 0; i < 16; i += 4)
        psum += (e[i] + e[i + 1]) + (e[i + 2] + e[i + 3]);
      unsigned pk[8];
#pragma unroll
      for (int j = 0; j < 8; ++j)
        asm("v_cvt_pk_bf16_f32 %0, %1, %2"
            : "=v"(pk[j]) : "v"(e[2 * j]), "v"(e[2 * j + 1]));
#pragma unroll
      for (int kbl = 0; kbl < 2; ++kbl) {
        unsigned w0 = pk[4 * kbl + 0], w2 = pk[4 * kbl + 2];
        unsigned w1 = pk[4 * kbl + 1], w3 = pk[4 * kbl + 3];
        asm("v_permlane32_swap_b32 %0, %1" : "+v"(w0), "+v"(w2));
        asm("v_permlane32_swap_b32 %0, %1" : "+v"(w1), "+v"(w3));
        uint32x4 wbits = {w0, w1, w2, w3};
        bp[2 * tt + kbl] = __builtin_bit_cast(short8, wbits);
      }
    }

    // O^T += V^T·P
    __builtin_amdgcn_s_setprio(1);
#pragma unroll
    for (int kb = 0; kb < 4; ++kb) {
      short8 av = *(const short8*)&sVa[cur][kb * 2 + half][l31 * 8];
      o = __builtin_amdgcn_mfma_f32_32x32x16_bf16(av, bp[kb], o, 0, 0, 0);
    }
    __builtin_amdgcn_s_setprio(0);

    __syncthreads();
  }

  float denom = psum + __shfl_xor(psum, 32);
  float inv = 1.f / denom;
  // (b) transpose the wave's 32x32 fp16 tile through LDS, then store
  //     coalesced: lanes 0-7 cover one full 64B row-line, 8 rows/instr.
#pragma unroll
  for (int rg = 0; rg < 4; ++rg) {
    ushort h4[4];
#pragma unroll
    for (int j = 0; j < 4; ++j) h4[j] = f2h(o[rg * 4 + j] * inv);
    *(uint2*)&tb[w][l31][rg * 8 + half * 4] = *(uint2*)h4;
  }
  int rr = lane >> 3, cc = (lane & 7) * 4;
  size_t gb = ((size_t)b * NN + q0 + w * 32) * 256 + h * 32 + cc;
#pragma unroll
  for (int it = 0; it < 4; ++it) {
    int r = it * 8 + rr;
    uint2 v = *(uint2*)&tb[w][r][cc];
    *(uint2*)&aH[gb + (size_t)r * 256] = v;
  }
}

// ---------------------------------------------------------------------------
// 4) proj GEMM — fp16 path (1 MFMA/slice, validated R11). 64x64 tiles,
//    double-buffered single-barrier, depth-2 register pipeline.
__global__ __launch_bounds__(256) void gemm_proj(
    const ushort* __restrict__ A, const ushort* __restrict__ Whi,
    const float* __restrict__ bias, float* __restrict__ out) {
  __shared__ ushort smem[2][2 * 64 * 40];
  constexpr int OA = 0, OW = 64 * 40;
  int bid = blockIdx.x;
  int r0 = (bid >> 2) * 64, c0 = (bid & 3) * 64;

  int t = threadIdx.x;
  int lane = t & 63, w = t >> 6;
  int l31 = lane & 31, half = lane >> 5;
  int wr = w >> 1, wc = w & 1;
  int rowA = t >> 2, kq = (t & 3) * 8;

  f32x16 acc;
#pragma unroll
  for (int i = 0; i < 16; ++i) acc[i] = 0.f;

  short8 ra[2], rwh[2];
  auto prefetch = [&](int kc, int s) {
    ra[s]  = *(const short8*)&A[(size_t)(r0 + rowA) * 256 + kc + kq];
    rwh[s] = *(const short8*)&Whi[(size_t)(c0 + rowA) * 256 + kc + kq];
  };
  auto store = [&](ushort* buf, int s) {
    *(short8*)&buf[OA + rowA * 40 + kq] = ra[s];
    *(short8*)&buf[OW + rowA * 40 + kq] = rwh[s];
  };

  prefetch(0, 0);
  store(smem[0], 0);
  prefetch(32, 1);
  __syncthreads();
#pragma unroll
  for (int i = 0; i < 8; ++i) {
    ushort* cur = smem[i & 1];
    ushort* nxt = smem[(i & 1) ^ 1];
    if (i < 7) store(nxt, (i + 1) & 1);
    if (i < 6) prefetch((i + 2) * 32, i & 1);
#pragma unroll
    for (int ks = 0; ks < 2; ++ks) {
      int ro = (wr * 32 + l31) * 40 + ks * 16 + half * 8;
      int co = (wc * 32 + l31) * 40 + ks * 16 + half * 8;
      half8 af = __builtin_bit_cast(half8, *(const short8*)&cur[OA + ro]);
      half8 wf = __builtin_bit_cast(half8, *(const short8*)&cur[OW + co]);
      acc = __builtin_amdgcn_mfma_f32_32x32x16_f16(af, wf, acc, 0, 0, 0);
    }
    __syncthreads();
  }

#pragma unroll
  for (int i = 0; i < 16; ++i) {
    int rl = (i & 3) + 8 * (i >> 2) + 4 * half;
    int r = r0 + wr * 32 + rl;
    int c = c0 + wc * 32 + l31;
    out[(size_t)r * 256 + c] = acc[i] + bias[c];
  }
}

// ---------------------------------------------------------------------------
extern "C" void kernel_launch(void* const* d_in, const int* in_sizes, int n_in,
                              void* d_out, int out_size, void* d_ws, size_t ws_size,
                              hipStream_t stream) {
  const float* x      = (const float*)d_in[0];
  const float* dw_w   = (const float*)d_in[1];
  const float* dw_b   = (const float*)d_in[2];
  const float* pw_w   = (const float*)d_in[3];
  const float* pw_b   = (const float*)d_in[4];
  const float* sr_w   = (const float*)d_in[5];
  const float* ln_g   = (const float*)d_in[6];
  const float* ln_b   = (const float*)d_in[7];
  const float* kv_w   = (const float*)d_in[8];
  const float* kv_b   = (const float*)d_in[9];
  const float* proj_w = (const float*)d_in[10];
  const float* proj_b = (const float*)d_in[11];
  float* out = (float*)d_out;

  char* ws = (char*)d_ws;
  ushort* q1b = (ushort*)(ws);                  // 16384x256 bf16  (8 MB)
  ushort* xsr = (ushort*)(ws + (8u << 20));     // 4096x256        (2 MB)
  ushort* qB  = (ushort*)(ws + (16u << 20));    // 32x4096x32      (8 MB)
  ushort* kBp = (ushort*)(ws + (24u << 20));    // 32x1024x32      (2 MB)
  ushort* vTp = (ushort*)(ws + (26u << 20));    // 32x32x1024      (2 MB)
  ushort* aH  = (ushort*)(ws + (28u << 20));    // 16384x256 fp16  (8 MB)
  ushort* pwB = (ushort*)(ws + (44u << 20));                 // 128 KB
  ushort* kvB = (ushort*)(ws + (44u << 20) + (512u << 10));  // 256 KB
  ushort* pjH = (ushort*)(ws + (45u << 20));                 // 128 KB fp16

  pre_fused<<<dim3(6400), 256, 0, stream>>>(x, dw_w, dw_b, sr_w, ln_g, ln_b,
                                            pw_w, kv_w, proj_w,
                                            q1b, xsr, pwB, kvB, pjH);
  gemm_qkv<<<dim3(1536), 256, 0, stream>>>(q1b, xsr, pwB, pw_b, kvB, kv_b,
                                           qB, kBp, vTp);
  attn_mfma<<<dim3(32, 32), 256, 0, stream>>>(qB, kBp, vTp, aH);
  gemm_proj<<<dim3(1024), 256, 0, stream>>>(aH, pjH, proj_b, out);
}